// Round 15
// baseline (359.769 us; speedup 1.0000x reference)
//
#include <hip/hip_runtime.h>
#include <hip/hip_bf16.h>

// Problem constants (AccessibilitySVIGNN): N=100000, A=32, CTX=5, H=64, E=1.6M
constexpr int A_DIM = 32;
constexpr int CTX_DIM = 5;
constexpr float EPS = 1e-5f;
constexpr int BCAP = 4096;  // per-bucket staging capacity (mean ~2046, sd ~45)
constexpr int EPB = 8192;   // edges per block in bucketA LDS sort
constexpr int NBP = 800;    // padded bucket count (NB = 782 for N=100000)

__device__ __forceinline__ float lrelu02(float x) { return x > 0.f ? x : 0.2f * x; }

__device__ __forceinline__ unsigned int f2bf_bits(float x) {
    __hip_bfloat16 h = __float2bfloat16(x);  // RNE
    return (unsigned int)reinterpret_cast<unsigned short&>(h);
}
__device__ __forceinline__ float bf_lo(unsigned int v) { return __uint_as_float(v << 16); }
__device__ __forceinline__ float bf_hi(unsigned int v) { return __uint_as_float(v & 0xffff0000u); }

// ======================= CSR build: bucket counting-sort =======================
__global__ __launch_bounds__(256) void k_bucketA(const int* __restrict__ ei, int E,
                                                 int* __restrict__ bcnt,
                                                 int* __restrict__ bstage, int NB) {
    __shared__ int hist[NBP];
    __shared__ int hexcl[NBP];
    __shared__ int cur[NBP];
    __shared__ int sd[256];
    __shared__ int stg[EPB];
    int tid = threadIdx.x;
    int base = blockIdx.x * EPB;
    int cnt = min(EPB, E - base);
    if (cnt <= 0) return;
    for (int i = tid; i < NBP; i += 256) hist[i] = 0;
    __syncthreads();
    for (int i = tid; i < cnt; i += 256) atomicAdd(&hist[ei[E + base + i] >> 7], 1);
    __syncthreads();
    {
        int idx0 = tid * 4;
        int v[4];
        int s = 0;
#pragma unroll
        for (int j = 0; j < 4; j++) {
            int idx = idx0 + j;
            v[j] = (idx < NB) ? hist[idx] : 0;
            s += v[j];
        }
        sd[tid] = s;
        __syncthreads();
        for (int off = 1; off < 256; off <<= 1) {
            int t = (tid >= off) ? sd[tid - off] : 0;
            __syncthreads();
            sd[tid] += t;
            __syncthreads();
        }
        int run = tid ? sd[tid - 1] : 0;
#pragma unroll
        for (int j = 0; j < 4; j++) {
            int idx = idx0 + j;
            if (idx < NBP) {
                hexcl[idx] = run;
                cur[idx] = run;
            }
            run += v[j];
        }
    }
    __syncthreads();
    for (int i = tid; i < cnt; i += 256) {
        int s = ei[base + i];
        int d = ei[E + base + i];
        int b = d >> 7;
        int pos = atomicAdd(&cur[b], 1);
        stg[pos] = ((d & 127) << 17) | s;
    }
    __syncthreads();
    for (int b = tid; b < NB; b += 256) {
        int c = hist[b];
        if (!c) continue;
        int gpos = atomicAdd(&bcnt[b * 16], c);
        int lim = min(c, BCAP - gpos);
        int lb = hexcl[b];
        int* dstp = bstage + (size_t)b * BCAP + gpos;
        for (int j = 0; j < lim; j++) dstp[j] = stg[lb + j];
    }
}

// Pass B: block per bucket (128 nodes). Computes its own exclusive prefix over
// capped bucket counts, then LDS degree count -> scan -> rowp/inv, LDS scatter
// into dst order, fully-coalesced dump to csrc.
__global__ __launch_bounds__(256) void k_bucketB(
    const int* __restrict__ bstage, const int* __restrict__ bcnt, int* __restrict__ rowp,
    float* __restrict__ inv, int* __restrict__ csrc, int n, int NB) {
    __shared__ int scur[128];
    __shared__ int sred[256];
    __shared__ int sstage[BCAP];
    int b = blockIdx.x, tid = threadIdx.x;
    int part = 0;
    for (int i = tid; i < b; i += 256) part += min(bcnt[i * 16], BCAP);
    sred[tid] = part;
    __syncthreads();
    for (int off = 128; off; off >>= 1) {
        if (tid < off) sred[tid] += sred[tid + off];
        __syncthreads();
    }
    int ebase = sred[0];
    int base_node = b << 7;
    int nn = min(128, n - base_node);
    int cntE = min(bcnt[b * 16], BCAP);
    const int* st = bstage + (size_t)b * BCAP;
    if (b == NB - 1 && tid == 0) rowp[n] = ebase + cntE;
    if (tid < 128) scur[tid] = 0;
    __syncthreads();
    for (int i = tid; i < cntE; i += 256) atomicAdd(&scur[st[i] >> 17], 1);
    __syncthreads();
    int deg = (tid < 128) ? scur[tid] : 0;
    __syncthreads();
    if (tid < 128) scur[tid] = deg;
    __syncthreads();
    for (int off = 1; off < 128; off <<= 1) {
        int t = (tid >= off && tid < 128) ? scur[tid - off] : 0;
        __syncthreads();
        if (tid < 128) scur[tid] += t;
        __syncthreads();
    }
    int excl = (tid < 128) ? (scur[tid] - deg) : 0;
    if (tid < nn) {
        rowp[base_node + tid] = ebase + excl;
        inv[base_node + tid] = rsqrtf((float)deg + 1.0f);  // +1 self-loop
    }
    if (tid < 128) scur[tid] = excl;
    __syncthreads();
    for (int i = tid; i < cntE; i += 256) {
        int p = st[i];
        int pos = atomicAdd(&scur[p >> 17], 1);
        sstage[pos] = p & 0x1FFFF;
    }
    __syncthreads();
    for (int i = tid; i < cntE; i += 256) csrc[ebase + i] = sstage[i];
}

// ============== context gate + LayerNorm (5->32->32 MLP, softmax, modulate, LN) ==============
__global__ __launch_bounds__(256) void k_gate(
    const float* __restrict__ accf, const float* __restrict__ ctxf,
    const float* __restrict__ w1, const float* __restrict__ b1,
    const float* __restrict__ w2, const float* __restrict__ b2,
    const float* __restrict__ aw, const float* __restrict__ ab,
    const float* __restrict__ base_imp, const float* __restrict__ lng,
    const float* __restrict__ lnb, float* __restrict__ xn_out, int n) {
    __shared__ float sh[4][64];
    int tid = threadIdx.x, wid = tid >> 6, lane = tid & 63;
    int l = lane & 31, half = lane >> 5;
    float w1c[CTX_DIM], w2c[32], awc[32];
#pragma unroll
    for (int k = 0; k < CTX_DIM; k++) w1c[k] = w1[k * 32 + l];
#pragma unroll
    for (int k = 0; k < 32; k++) w2c[k] = w2[k * 32 + l];
#pragma unroll
    for (int k = 0; k < 32; k++) awc[k] = aw[k * 32 + l];
    float b1v = b1[l], b2v = b2[l], abv = ab[l], bimp = base_imp[l];
    float lngv = lng[l], lnbv = lnb[l];
    float* s0 = sh[wid];
    const float4* s4 = (const float4*)s0;

    int npairs = (n + 1) >> 1;
    int gw = blockIdx.x * 4 + wid, nw = gridDim.x * 4;
    for (int pair = gw; pair < npairs; pair += nw) {
        int node = pair * 2 + half;
        bool valid = node < n;
        float cx0 = 0, cx1 = 0, cx2 = 0, cx3 = 0, cx4 = 0, xa = 0;
        if (valid) {
            cx0 = ctxf[node * CTX_DIM + 0];
            cx1 = ctxf[node * CTX_DIM + 1];
            cx2 = ctxf[node * CTX_DIM + 2];
            cx3 = ctxf[node * CTX_DIM + 3];
            cx4 = ctxf[node * CTX_DIM + 4];
            xa = accf[node * A_DIM + l];
        }
        float h1 = b1v + cx0 * w1c[0] + cx1 * w1c[1] + cx2 * w1c[2] + cx3 * w1c[3] + cx4 * w1c[4];
        s0[lane] = fmaxf(h1, 0.f);
        {
            float a0 = 0, a1 = 0, a2 = 0, a3 = 0;
#pragma unroll
            for (int k = 0; k < 8; k++) {
                float4 t = s4[half * 8 + k];
                a0 += t.x * w2c[4 * k];
                a1 += t.y * w2c[4 * k + 1];
                a2 += t.z * w2c[4 * k + 2];
                a3 += t.w * w2c[4 * k + 3];
            }
            s0[lane] = b2v + ((a0 + a1) + (a2 + a3));
        }
        float z;
        {
            float a0 = 0, a1 = 0, a2 = 0, a3 = 0;
#pragma unroll
            for (int k = 0; k < 8; k++) {
                float4 t = s4[half * 8 + k];
                a0 += t.x * awc[4 * k];
                a1 += t.y * awc[4 * k + 1];
                a2 += t.z * awc[4 * k + 2];
                a3 += t.w * awc[4 * k + 3];
            }
            z = abv + ((a0 + a1) + (a2 + a3));
        }
        float m = z;
#pragma unroll
        for (int off = 16; off; off >>= 1) m = fmaxf(m, __shfl_xor(m, off, 64));
        float ex = __expf(z - m);
        float ss = ex;
#pragma unroll
        for (int off = 16; off; off >>= 1) ss += __shfl_xor(ss, off, 64);
        float v = xa * (ex / ss) * bimp;
        float s1 = v, s2 = v * v;
#pragma unroll
        for (int off = 16; off; off >>= 1) {
            s1 += __shfl_xor(s1, off, 64);
            s2 += __shfl_xor(s2, off, 64);
        }
        float mu = s1 * (1.f / 32.f);
        float var = s2 * (1.f / 32.f) - mu * mu;
        float xn = (v - mu) * rsqrtf(var + EPS) * lngv + lnbv;
        if (valid) xn_out[(size_t)node * 32 + l] = xn;
    }
}

// ============== feature encoder: relu(relu(xn@fw1+fb1)@fw2+fb2) ==============
__global__ __launch_bounds__(256) void k_encode(
    const float* __restrict__ xn, const float* __restrict__ fw1, const float* __restrict__ fb1,
    const float* __restrict__ fw2, const float* __restrict__ fb2, float* __restrict__ xout,
    int n) {
    __shared__ float sh[4][128];
    int tid = threadIdx.x, wid = tid >> 6, lane = tid & 63;
    float f1c[32], f2c[64];
#pragma unroll
    for (int k = 0; k < 32; k++) f1c[k] = fw1[k * 64 + lane];
#pragma unroll
    for (int k = 0; k < 64; k++) f2c[k] = fw2[k * 64 + lane];
    float fb1v = fb1[lane], fb2v = fb2[lane];
    float* s0 = sh[wid];
    const float4* s4 = (const float4*)s0;

    int npairs = (n + 1) >> 1;
    int gw = blockIdx.x * 4 + wid, nw = gridDim.x * 4;
    int total = n * 32;
    for (int pair = gw; pair < npairs; pair += nw) {
        int idx = pair * 64 + lane;
        s0[lane] = (idx < total) ? xn[idx] : 0.f;
        float u0, u1;
        {
            float a0 = 0, a1 = 0, b0 = 0, b1 = 0;
#pragma unroll
            for (int k = 0; k < 8; k++) {
                float4 t = s4[k];
                float4 t2 = s4[8 + k];
                a0 += t.x * f1c[4 * k] + t.y * f1c[4 * k + 1];
                a1 += t.z * f1c[4 * k + 2] + t.w * f1c[4 * k + 3];
                b0 += t2.x * f1c[4 * k] + t2.y * f1c[4 * k + 1];
                b1 += t2.z * f1c[4 * k + 2] + t2.w * f1c[4 * k + 3];
            }
            u0 = fmaxf(fb1v + a0 + a1, 0.f);
            u1 = fmaxf(fb1v + b0 + b1, 0.f);
        }
        s0[lane] = u0;
        s0[64 + lane] = u1;
        float o0, o1;
        {
            float a0 = 0, a1 = 0, b0 = 0, b1 = 0;
#pragma unroll
            for (int k = 0; k < 16; k++) {
                float4 t = s4[k];
                float4 t2 = s4[16 + k];
                a0 += t.x * f2c[4 * k] + t.y * f2c[4 * k + 1];
                a1 += t.z * f2c[4 * k + 2] + t.w * f2c[4 * k + 3];
                b0 += t2.x * f2c[4 * k] + t2.y * f2c[4 * k + 1];
                b1 += t2.z * f2c[4 * k + 2] + t2.w * f2c[4 * k + 3];
            }
            o0 = fmaxf(fb2v + a0 + a1, 0.f);
            o1 = fmaxf(fb2v + b0 + b1, 0.f);
        }
        int n0 = pair * 2;
        xout[(size_t)n0 * 64 + lane] = o0;
        if (n0 + 1 < n) xout[(size_t)(n0 + 1) * 64 + lane] = o1;
    }
}

// ================ dense transform h = x @ W (64 -> COUT), bf16 output ================
template <int COUT, bool DO_ATTN, bool SCALE>
__global__ __launch_bounds__(256) void k_transform(
    const float* __restrict__ x, const float* __restrict__ w,
    const float* __restrict__ asrc, const float* __restrict__ adst,
    const float* __restrict__ inv, __hip_bfloat16* __restrict__ h,
    float* __restrict__ attn, int n) {
    constexpr int NPG = 64 / COUT;  // nodes per wave
    __shared__ __align__(16) float scr[4][NPG * 64];
    int tid = threadIdx.x, wid = tid >> 6, lane = tid & 63;
    int ch = lane % COUT;
    int sub = lane / COUT;
    float wr[64];
#pragma unroll
    for (int k = 0; k < 64; k++) wr[k] = w[k * COUT + ch];
    float as_r = 0.f, ad_r = 0.f;
    if (DO_ATTN) {
        as_r = asrc[lane];
        ad_r = adst[lane];
    }
    int ngroups = (n + NPG - 1) / NPG;
    int gw = blockIdx.x * 4 + wid, nw = gridDim.x * 4;
    int total = n * 64;
    unsigned int* h2 = (unsigned int*)h;
    for (int g = gw; g < ngroups; g += nw) {
        int base = g * NPG * 64;
#pragma unroll
        for (int i = 0; i < NPG; i++) {
            int idx = i * 64 + lane;
            scr[wid][idx] = (base + idx < total) ? x[base + idx] : 0.f;
        }
        float acc0 = 0.f, acc1 = 0.f;
        const float4* sp4 = (const float4*)(&scr[wid][sub * 64]);
#pragma unroll
        for (int k = 0; k < 16; k++) {
            float4 t = sp4[k];
            acc0 += t.x * wr[4 * k] + t.y * wr[4 * k + 1];
            acc1 += t.z * wr[4 * k + 2] + t.w * wr[4 * k + 3];
        }
        float acc = acc0 + acc1;
        int node = g * NPG + sub;
        if (SCALE) acc *= (node < n) ? inv[node] : 0.f;
        unsigned int mine = f2bf_bits(acc);
        unsigned int oth = (unsigned int)__shfl_xor((int)mine, 1, 64);
        if ((ch & 1) == 0 && node < n)
            h2[(size_t)node * (COUT / 2) + (ch >> 1)] = mine | (oth << 16);
        if (DO_ATTN) {
            float ps = acc * as_r, pd = acc * ad_r;
#pragma unroll
            for (int off = 16; off; off >>= 1) {
                ps += __shfl_xor(ps, off, 64);
                pd += __shfl_xor(pd, off, 64);
            }
            if ((lane & 31) == 0 && node < n) {
                int hd = lane >> 5;
                attn[node * 4 + hd] = ps;       // alpha_src
                attn[node * 4 + 2 + hd] = pd;   // alpha_dst
            }
        }
    }
}

// ================ GCN aggregation + bias + BN + ReLU (pre-scaled bf16 h') ================
// Maskless (dummy row); 8-edge step quantization (deg~Poisson(16) -> less waste).
template <int C>
__global__ __launch_bounds__(256) void k_gcn_agg(
    const __hip_bfloat16* __restrict__ h, const int* __restrict__ rowp,
    const int* __restrict__ csrc, const float* __restrict__ inv,
    const float* __restrict__ bias, const float* __restrict__ bg,
    const float* __restrict__ bb, const float* __restrict__ bm,
    const float* __restrict__ bv, float* __restrict__ out, int n, int dummy) {
    constexpr int LPE = C / 2;
    constexpr int NE = 64 / LPE;  // edges in flight
    constexpr int UN = 8 / NE;    // groups per 8-edge step
    int tid = threadIdx.x, lane = tid & 63;
    int node = blockIdx.x * 4 + (tid >> 6);
    if (node >= n) return;
    float invd = inv[node];
    int e0 = rowp[node], e1 = rowp[node + 1];
    int l = lane & (LPE - 1);
    int grp = lane / LPE;
    const unsigned int* h2 = (const unsigned int*)h;
    float acc0 = 0.f, acc1 = 0.f;
    for (int cb = e0; cb < e1; cb += 64) {
        int kn = min(64, e1 - cb);
        int s_l = (lane < kn) ? csrc[cb + lane] : dummy;  // dummy row = zeros
        for (int kb = 0; kb < kn; kb += 8) {
            unsigned int v[UN];
#pragma unroll
            for (int i = 0; i < UN; i++) {
                int k = kb + i * NE + grp;
                int s = __shfl(s_l, k, 64);
                v[i] = h2[(size_t)s * LPE + l];
            }
#pragma unroll
            for (int i = 0; i < UN; i++) {
                acc0 += bf_lo(v[i]);
                acc1 += bf_hi(v[i]);
            }
        }
    }
#pragma unroll
    for (int off = LPE; off < 64; off <<= 1) {
        acc0 += __shfl_xor(acc0, off, 64);
        acc1 += __shfl_xor(acc1, off, 64);
    }
    unsigned int sv = h2[(size_t)node * LPE + l];
    acc0 = (acc0 + bf_lo(sv)) * invd;
    acc1 = (acc1 + bf_hi(sv)) * invd;
    if (grp == 0) {
        int c0 = 2 * l;
        float sc0 = bg[c0] * rsqrtf(bv[c0] + EPS);
        float sc1 = bg[c0 + 1] * rsqrtf(bv[c0 + 1] + EPS);
        float r0 = (acc0 + bias[c0] - bm[c0]) * sc0 + bb[c0];
        float r1 = (acc1 + bias[c0 + 1] - bm[c0 + 1]) * sc1 + bb[c0 + 1];
        ((float2*)out)[(size_t)node * LPE + l] = make_float2(fmaxf(r0, 0.f), fmaxf(r1, 0.f));
    }
}

// ================ GAT aggregation + bias + BN + ReLU (bf16 h) ================
// No segment-max (exp(e)/sum(exp(e)) direct, clamp 60); 8-edge step quantization.
__global__ __launch_bounds__(256) void k_gat_agg(
    const __hip_bfloat16* __restrict__ h, const int* __restrict__ rowp,
    const int* __restrict__ csrc, const float* __restrict__ attn,
    const float* __restrict__ bias, const float* __restrict__ bg,
    const float* __restrict__ bb, const float* __restrict__ bm,
    const float* __restrict__ bv, float* __restrict__ out, int n) {
    __shared__ uint2 sed[4][64];
    int tid = threadIdx.x, lane = tid & 63, wid = tid >> 6;
    int node = blockIdx.x * 4 + wid;
    if (node >= n) return;
    uint2* se = sed[wid];
    const float4* a4p = (const float4*)attn;
    float4 ad = a4p[node];
    float ad0 = ad.z, ad1 = ad.w;
    float exs0 = __expf(fminf(lrelu02(ad.x + ad0), 60.f));  // self edge
    float exs1 = __expf(fminf(lrelu02(ad.y + ad1), 60.f));
    int e0 = rowp[node], e1 = rowp[node + 1];
    int deg = e1 - e0;
    int kn0 = min(deg, 64);
    int s_l = (lane < kn0) ? csrc[e0 + lane] : node;
    float4 a_l = a4p[s_l];
    float ex0 = (lane < kn0) ? __expf(fminf(lrelu02(a_l.x + ad0), 60.f)) : 0.f;
    float ex1 = (lane < kn0) ? __expf(fminf(lrelu02(a_l.y + ad1), 60.f)) : 0.f;
    float t0 = ex0, t1 = ex1;
    se[lane] = make_uint2((unsigned int)s_l, f2bf_bits(ex0) | (f2bf_bits(ex1) << 16));
    int l = lane & 31, grp = lane >> 5;
    bool hd2 = l >= 16;  // channels 2l,2l+1 belong to head (l>=16)
    const unsigned int* h2 = (const unsigned int*)h;
    float acc0 = 0.f, acc1 = 0.f;
    for (int kb = 0; kb < kn0; kb += 8) {
        unsigned int v[4];
        float wg[4];
#pragma unroll
        for (int i = 0; i < 4; i++) {
            int k = kb + i * 2 + grp;
            uint2 e = se[k];  // broadcast within group (2-way: free)
            wg[i] = hd2 ? bf_hi(e.y) : bf_lo(e.y);
            v[i] = h2[(size_t)e.x * 32 + l];
        }
#pragma unroll
        for (int i = 0; i < 4; i++) {
            acc0 += wg[i] * bf_lo(v[i]);
            acc1 += wg[i] * bf_hi(v[i]);
        }
    }
    // extra chunks (deg > 64)
    for (int cb = e0 + 64; cb < e1; cb += 64) {
        int kn = min(64, e1 - cb);
        int s_c = (lane < kn) ? csrc[cb + lane] : node;
        float4 a_c = a4p[s_c];
        float c0 = (lane < kn) ? __expf(fminf(lrelu02(a_c.x + ad0), 60.f)) : 0.f;
        float c1 = (lane < kn) ? __expf(fminf(lrelu02(a_c.y + ad1), 60.f)) : 0.f;
        t0 += c0;
        t1 += c1;
        se[lane] = make_uint2((unsigned int)s_c, f2bf_bits(c0) | (f2bf_bits(c1) << 16));
        for (int kb = 0; kb < kn; kb += 8) {
            unsigned int v[4];
            float wg[4];
#pragma unroll
            for (int i = 0; i < 4; i++) {
                int k = kb + i * 2 + grp;
                uint2 e = se[k];
                wg[i] = hd2 ? bf_hi(e.y) : bf_lo(e.y);
                v[i] = h2[(size_t)e.x * 32 + l];
            }
#pragma unroll
            for (int i = 0; i < 4; i++) {
                acc0 += wg[i] * bf_lo(v[i]);
                acc1 += wg[i] * bf_hi(v[i]);
            }
        }
    }
#pragma unroll
    for (int off = 32; off; off >>= 1) {
        t0 += __shfl_xor(t0, off, 64);
        t1 += __shfl_xor(t1, off, 64);
    }
    t0 += exs0;
    t1 += exs1;
    acc0 += __shfl_xor(acc0, 32, 64);
    acc1 += __shfl_xor(acc1, 32, 64);
    unsigned int sv = h2[(size_t)node * 32 + l];
    float ws = hd2 ? exs1 : exs0;
    acc0 += ws * bf_lo(sv);
    acc1 += ws * bf_hi(sv);
    float rsh = hd2 ? (1.f / (t1 + 1e-16f)) : (1.f / (t0 + 1e-16f));
    acc0 *= rsh;
    acc1 *= rsh;
    if (grp == 0) {
        int c0 = 2 * l;
        float sc0 = bg[c0] * rsqrtf(bv[c0] + EPS);
        float sc1 = bg[c0 + 1] * rsqrtf(bv[c0 + 1] + EPS);
        float r0 = (acc0 + bias[c0] - bm[c0]) * sc0 + bb[c0];
        float r1 = (acc1 + bias[c0 + 1] - bm[c0 + 1]) * sc1 + bb[c0 + 1];
        ((float2*)out)[(size_t)node * 32 + l] = make_float2(fmaxf(r0, 0.f), fmaxf(r1, 0.f));
    }
}

// ================ SVI head: relu(x@W1+b1)@W2+b2 -> sigmoid ================
__global__ __launch_bounds__(256) void k_head(
    const float* __restrict__ x, const float* __restrict__ w1, const float* __restrict__ b1,
    const float* __restrict__ w2, const float* __restrict__ b2, float* __restrict__ out, int n) {
    __shared__ float sw1[512], sb1[16], sw2[16];
    __shared__ float sb2v;
    __shared__ float scr[4][64];
    int tid = threadIdx.x;
    for (int i = tid; i < 512; i += 256) sw1[i] = w1[i];
    if (tid < 16) {
        sb1[tid] = b1[tid];
        sw2[tid] = w2[tid];
    }
    if (tid == 0) sb2v = b2[0];
    __syncthreads();
    int wid = tid >> 6, lane = tid & 63;
    int half = lane >> 5;
    int np = (n + 1) >> 1;
    int gw = blockIdx.x * 4 + wid, nw = gridDim.x * 4;
    int total = n * 32;
    for (int g = gw; g < np; g += nw) {
        int idx = g * 64 + lane;
        scr[wid][lane] = (idx < total) ? x[idx] : 0.f;
        int j = lane & 15;
        float u = sb1[j];
#pragma unroll
        for (int k = 0; k < 32; k++) u += scr[wid][half * 32 + k] * sw1[k * 16 + j];
        u = fmaxf(u, 0.f);
        float p = u * sw2[j];
#pragma unroll
        for (int off = 8; off; off >>= 1) p += __shfl_xor(p, off, 64);
        int node = g * 2 + half;
        if ((lane & 31) == 0 && node < n) {
            float z = p + sb2v;
            out[node] = 1.f / (1.f + __expf(-z));
        }
    }
}

// ======================= launcher =======================
extern "C" void kernel_launch(void* const* d_in, const int* in_sizes, int n_in,
                              void* d_out, int out_size, void* d_ws, size_t ws_size,
                              hipStream_t stream) {
    const float* accf = (const float*)d_in[0];
    const float* ctxf = (const float*)d_in[1];
    const int* ei = (const int*)d_in[2];
    const float* cg_w1 = (const float*)d_in[3];
    const float* cg_b1 = (const float*)d_in[4];
    const float* cg_w2 = (const float*)d_in[5];
    const float* cg_b2 = (const float*)d_in[6];
    const float* cg_aw = (const float*)d_in[7];
    const float* cg_ab = (const float*)d_in[8];
    const float* base_imp = (const float*)d_in[9];
    const float* ln_g = (const float*)d_in[10];
    const float* ln_b = (const float*)d_in[11];
    const float* fe_w1 = (const float*)d_in[12];
    const float* fe_b1 = (const float*)d_in[13];
    const float* fe_w2 = (const float*)d_in[14];
    const float* fe_b2 = (const float*)d_in[15];
    const float* gcn1_w = (const float*)d_in[16];
    const float* gcn1_b = (const float*)d_in[17];
    const float* bn1_g = (const float*)d_in[18];
    const float* bn1_b = (const float*)d_in[19];
    const float* bn1_m = (const float*)d_in[20];
    const float* bn1_v = (const float*)d_in[21];
    const float* gat_w = (const float*)d_in[22];
    const float* gat_asrc = (const float*)d_in[23];
    const float* gat_adst = (const float*)d_in[24];
    const float* gat_b = (const float*)d_in[25];
    const float* bn2_g = (const float*)d_in[26];
    const float* bn2_b = (const float*)d_in[27];
    const float* bn2_m = (const float*)d_in[28];
    const float* bn2_v = (const float*)d_in[29];
    const float* gcn2_w = (const float*)d_in[30];
    const float* gcn2_b = (const float*)d_in[31];
    const float* bn3_g = (const float*)d_in[32];
    const float* bn3_b = (const float*)d_in[33];
    const float* bn3_m = (const float*)d_in[34];
    const float* bn3_v = (const float*)d_in[35];
    const float* sp_w1 = (const float*)d_in[36];
    const float* sp_b1 = (const float*)d_in[37];
    const float* sp_w2 = (const float*)d_in[38];
    const float* sp_b2 = (const float*)d_in[39];

    int n = in_sizes[0] / A_DIM;  // 100000
    int E = in_sizes[2] / 2;      // 1600000
    int NB = (n + 127) >> 7;      // 782 buckets of 128 nodes

    char* p = (char*)d_ws;
    auto alloc = [&](size_t bytes) -> void* {
        void* r = (void*)p;
        p += (bytes + 255) & ~(size_t)255;
        return r;
    };
    float* X = (float*)alloc((size_t)n * 64 * 4);
    __hip_bfloat16* Hb = (__hip_bfloat16*)alloc((size_t)n * 64 * 2 + 256);  // +dummy rows
    float* attn = (float*)alloc((size_t)n * 4 * 4);
    float* XN = (float*)alloc((size_t)n * 32 * 4);
    int* rowp = (int*)alloc((size_t)(n + 1) * 4);
    float* inv = (float*)alloc((size_t)n * 4);
    int* csrc = (int*)alloc((size_t)E * 4);
    int* bcnt = (int*)alloc((size_t)NB * 16 * 4);  // padded: 1 counter / 64B line
    int* bstage = (int*)alloc((size_t)NB * BCAP * 4);

    // --- CSR build (bucket counting sort; LDS-sorted pass A) ---
    hipMemsetAsync(bcnt, 0, (size_t)NB * 16 * 4, stream);
    // zero dummy rows: bytes [128n, 128n+192) cover C=64 dummy (row n) and
    // C=32 dummy (row 2n+2); no transform ever writes >= byte 128n.
    hipMemsetAsync((char*)Hb + (size_t)128 * n, 0, 192, stream);
    k_bucketA<<<(E + EPB - 1) / EPB, 256, 0, stream>>>(ei, E, bcnt, bstage, NB);
    k_bucketB<<<NB, 256, 0, stream>>>(bstage, bcnt, rowp, inv, csrc, n, NB);

    // --- node pipeline ---
    k_gate<<<1024, 256, 0, stream>>>(accf, ctxf, cg_w1, cg_b1, cg_w2, cg_b2, cg_aw, cg_ab,
                                     base_imp, ln_g, ln_b, XN, n);
    k_encode<<<1024, 256, 0, stream>>>(XN, fe_w1, fe_b1, fe_w2, fe_b2, X, n);
    // GCN1 (pre-scaled h'); dummy row = n
    k_transform<64, false, true><<<1024, 256, 0, stream>>>(X, gcn1_w, nullptr, nullptr, inv, Hb,
                                                           nullptr, n);
    k_gcn_agg<64><<<(n + 3) / 4, 256, 0, stream>>>(Hb, rowp, csrc, inv, gcn1_b, bn1_g, bn1_b,
                                                   bn1_m, bn1_v, X, n, n);
    // GAT (unscaled h)
    k_transform<64, true, false><<<1024, 256, 0, stream>>>(X, gat_w, gat_asrc, gat_adst, nullptr,
                                                           Hb, attn, n);
    k_gat_agg<<<(n + 3) / 4, 256, 0, stream>>>(Hb, rowp, csrc, attn, gat_b, bn2_g, bn2_b, bn2_m,
                                               bn2_v, X, n);
    // GCN2 (pre-scaled h'); dummy row = 2n+2
    k_transform<32, false, true><<<1024, 256, 0, stream>>>(X, gcn2_w, nullptr, nullptr, inv, Hb,
                                                           nullptr, n);
    k_gcn_agg<32><<<(n + 3) / 4, 256, 0, stream>>>(Hb, rowp, csrc, inv, gcn2_b, bn3_g, bn3_b,
                                                   bn3_m, bn3_v, X, n, 2 * n + 2);
    // head
    k_head<<<512, 256, 0, stream>>>(X, sp_w1, sp_b1, sp_w2, sp_b2, (float*)d_out, n);
}

// Round 16
// 347.436 us; speedup vs baseline: 1.0355x; 1.0355x over previous
//
#include <hip/hip_runtime.h>
#include <hip/hip_bf16.h>

// Problem constants (AccessibilitySVIGNN): N=100000, A=32, CTX=5, H=64, E=1.6M
constexpr int A_DIM = 32;
constexpr int CTX_DIM = 5;
constexpr float EPS = 1e-5f;
constexpr int BCAP = 4096;  // per-bucket staging capacity (mean ~2046, sd ~45)
constexpr int EPB = 8192;   // edges per block in bucketA LDS sort
constexpr int NBP = 800;    // padded bucket count (NB = 782 for N=100000)

__device__ __forceinline__ float lrelu02(float x) { return x > 0.f ? x : 0.2f * x; }

__device__ __forceinline__ unsigned int f2bf_bits(float x) {
    __hip_bfloat16 h = __float2bfloat16(x);  // RNE
    return (unsigned int)reinterpret_cast<unsigned short&>(h);
}
__device__ __forceinline__ float bf_lo(unsigned int v) { return __uint_as_float(v << 16); }
__device__ __forceinline__ float bf_hi(unsigned int v) { return __uint_as_float(v & 0xffff0000u); }

// ======================= CSR build: bucket counting-sort =======================
// Pass A: edges register-cached (32/thread) -> single global read; LDS
// bucket-sort; per-bucket contiguous burst flush at atomically-claimed position.
__global__ __launch_bounds__(256) void k_bucketA(const int* __restrict__ ei, int E,
                                                 int* __restrict__ bcnt,
                                                 int* __restrict__ bstage, int NB) {
    __shared__ int hist[NBP];
    __shared__ int hexcl[NBP];
    __shared__ int cur[NBP];
    __shared__ int sd[256];
    __shared__ int stg[EPB];
    int tid = threadIdx.x;
    int base = blockIdx.x * EPB;
    int cnt = min(EPB, E - base);
    if (cnt <= 0) return;
    for (int i = tid; i < NBP; i += 256) hist[i] = 0;
    __syncthreads();
    // single-pass load into registers + histogram
    int sreg[32], dreg[32];
#pragma unroll
    for (int j = 0; j < 32; j++) {
        int i = tid + j * 256;
        bool ok = i < cnt;
        sreg[j] = ok ? ei[base + i] : 0;
        dreg[j] = ok ? ei[E + base + i] : -1;
        if (ok) atomicAdd(&hist[dreg[j] >> 7], 1);
    }
    __syncthreads();
    {
        int idx0 = tid * 4;
        int v[4];
        int s = 0;
#pragma unroll
        for (int j = 0; j < 4; j++) {
            int idx = idx0 + j;
            v[j] = (idx < NB) ? hist[idx] : 0;
            s += v[j];
        }
        sd[tid] = s;
        __syncthreads();
        for (int off = 1; off < 256; off <<= 1) {
            int t = (tid >= off) ? sd[tid - off] : 0;
            __syncthreads();
            sd[tid] += t;
            __syncthreads();
        }
        int run = tid ? sd[tid - 1] : 0;
#pragma unroll
        for (int j = 0; j < 4; j++) {
            int idx = idx0 + j;
            if (idx < NBP) {
                hexcl[idx] = run;
                cur[idx] = run;
            }
            run += v[j];
        }
    }
    __syncthreads();
    // scatter from registers into LDS, bucket-sorted
#pragma unroll
    for (int j = 0; j < 32; j++) {
        int i = tid + j * 256;
        if (i < cnt) {
            int b = dreg[j] >> 7;
            int pos = atomicAdd(&cur[b], 1);
            stg[pos] = ((dreg[j] & 127) << 17) | sreg[j];
        }
    }
    __syncthreads();
    for (int b = tid; b < NB; b += 256) {
        int c = hist[b];
        if (!c) continue;
        int gpos = atomicAdd(&bcnt[b * 16], c);
        int lim = min(c, BCAP - gpos);
        int lb = hexcl[b];
        int* dstp = bstage + (size_t)b * BCAP + gpos;
        for (int j = 0; j < lim; j++) dstp[j] = stg[lb + j];
    }
}

// Pass B: block per bucket (128 nodes). Computes its own exclusive prefix over
// capped bucket counts, then LDS degree count -> scan -> rowp/inv, LDS scatter
// into dst order, fully-coalesced dump to csrc.
__global__ __launch_bounds__(256) void k_bucketB(
    const int* __restrict__ bstage, const int* __restrict__ bcnt, int* __restrict__ rowp,
    float* __restrict__ inv, int* __restrict__ csrc, int n, int NB) {
    __shared__ int scur[128];
    __shared__ int sred[256];
    __shared__ int sstage[BCAP];
    int b = blockIdx.x, tid = threadIdx.x;
    int part = 0;
    for (int i = tid; i < b; i += 256) part += min(bcnt[i * 16], BCAP);
    sred[tid] = part;
    __syncthreads();
    for (int off = 128; off; off >>= 1) {
        if (tid < off) sred[tid] += sred[tid + off];
        __syncthreads();
    }
    int ebase = sred[0];
    int base_node = b << 7;
    int nn = min(128, n - base_node);
    int cntE = min(bcnt[b * 16], BCAP);
    const int* st = bstage + (size_t)b * BCAP;
    if (b == NB - 1 && tid == 0) rowp[n] = ebase + cntE;
    if (tid < 128) scur[tid] = 0;
    __syncthreads();
    for (int i = tid; i < cntE; i += 256) atomicAdd(&scur[st[i] >> 17], 1);
    __syncthreads();
    int deg = (tid < 128) ? scur[tid] : 0;
    __syncthreads();
    if (tid < 128) scur[tid] = deg;
    __syncthreads();
    for (int off = 1; off < 128; off <<= 1) {
        int t = (tid >= off && tid < 128) ? scur[tid - off] : 0;
        __syncthreads();
        if (tid < 128) scur[tid] += t;
        __syncthreads();
    }
    int excl = (tid < 128) ? (scur[tid] - deg) : 0;
    if (tid < nn) {
        rowp[base_node + tid] = ebase + excl;
        inv[base_node + tid] = rsqrtf((float)deg + 1.0f);  // +1 self-loop
    }
    if (tid < 128) scur[tid] = excl;
    __syncthreads();
    for (int i = tid; i < cntE; i += 256) {
        int p = st[i];
        int pos = atomicAdd(&scur[p >> 17], 1);
        sstage[pos] = p & 0x1FFFF;
    }
    __syncthreads();
    for (int i = tid; i < cntE; i += 256) csrc[ebase + i] = sstage[i];
}

// ============== context gate + LayerNorm (5->32->32 MLP, softmax, modulate, LN) ==============
__global__ __launch_bounds__(256) void k_gate(
    const float* __restrict__ accf, const float* __restrict__ ctxf,
    const float* __restrict__ w1, const float* __restrict__ b1,
    const float* __restrict__ w2, const float* __restrict__ b2,
    const float* __restrict__ aw, const float* __restrict__ ab,
    const float* __restrict__ base_imp, const float* __restrict__ lng,
    const float* __restrict__ lnb, float* __restrict__ xn_out, int n) {
    __shared__ float sh[4][64];
    int tid = threadIdx.x, wid = tid >> 6, lane = tid & 63;
    int l = lane & 31, half = lane >> 5;
    float w1c[CTX_DIM], w2c[32], awc[32];
#pragma unroll
    for (int k = 0; k < CTX_DIM; k++) w1c[k] = w1[k * 32 + l];
#pragma unroll
    for (int k = 0; k < 32; k++) w2c[k] = w2[k * 32 + l];
#pragma unroll
    for (int k = 0; k < 32; k++) awc[k] = aw[k * 32 + l];
    float b1v = b1[l], b2v = b2[l], abv = ab[l], bimp = base_imp[l];
    float lngv = lng[l], lnbv = lnb[l];
    float* s0 = sh[wid];
    const float4* s4 = (const float4*)s0;

    int npairs = (n + 1) >> 1;
    int gw = blockIdx.x * 4 + wid, nw = gridDim.x * 4;
    for (int pair = gw; pair < npairs; pair += nw) {
        int node = pair * 2 + half;
        bool valid = node < n;
        float cx0 = 0, cx1 = 0, cx2 = 0, cx3 = 0, cx4 = 0, xa = 0;
        if (valid) {
            cx0 = ctxf[node * CTX_DIM + 0];
            cx1 = ctxf[node * CTX_DIM + 1];
            cx2 = ctxf[node * CTX_DIM + 2];
            cx3 = ctxf[node * CTX_DIM + 3];
            cx4 = ctxf[node * CTX_DIM + 4];
            xa = accf[node * A_DIM + l];
        }
        float h1 = b1v + cx0 * w1c[0] + cx1 * w1c[1] + cx2 * w1c[2] + cx3 * w1c[3] + cx4 * w1c[4];
        s0[lane] = fmaxf(h1, 0.f);
        {
            float a0 = 0, a1 = 0, a2 = 0, a3 = 0;
#pragma unroll
            for (int k = 0; k < 8; k++) {
                float4 t = s4[half * 8 + k];
                a0 += t.x * w2c[4 * k];
                a1 += t.y * w2c[4 * k + 1];
                a2 += t.z * w2c[4 * k + 2];
                a3 += t.w * w2c[4 * k + 3];
            }
            s0[lane] = b2v + ((a0 + a1) + (a2 + a3));
        }
        float z;
        {
            float a0 = 0, a1 = 0, a2 = 0, a3 = 0;
#pragma unroll
            for (int k = 0; k < 8; k++) {
                float4 t = s4[half * 8 + k];
                a0 += t.x * awc[4 * k];
                a1 += t.y * awc[4 * k + 1];
                a2 += t.z * awc[4 * k + 2];
                a3 += t.w * awc[4 * k + 3];
            }
            z = abv + ((a0 + a1) + (a2 + a3));
        }
        float m = z;
#pragma unroll
        for (int off = 16; off; off >>= 1) m = fmaxf(m, __shfl_xor(m, off, 64));
        float ex = __expf(z - m);
        float ss = ex;
#pragma unroll
        for (int off = 16; off; off >>= 1) ss += __shfl_xor(ss, off, 64);
        float v = xa * (ex / ss) * bimp;
        float s1 = v, s2 = v * v;
#pragma unroll
        for (int off = 16; off; off >>= 1) {
            s1 += __shfl_xor(s1, off, 64);
            s2 += __shfl_xor(s2, off, 64);
        }
        float mu = s1 * (1.f / 32.f);
        float var = s2 * (1.f / 32.f) - mu * mu;
        float xn = (v - mu) * rsqrtf(var + EPS) * lngv + lnbv;
        if (valid) xn_out[(size_t)node * 32 + l] = xn;
    }
}

// ============== feature encoder: relu(relu(xn@fw1+fb1)@fw2+fb2) ==============
__global__ __launch_bounds__(256) void k_encode(
    const float* __restrict__ xn, const float* __restrict__ fw1, const float* __restrict__ fb1,
    const float* __restrict__ fw2, const float* __restrict__ fb2, float* __restrict__ xout,
    int n) {
    __shared__ float sh[4][128];
    int tid = threadIdx.x, wid = tid >> 6, lane = tid & 63;
    float f1c[32], f2c[64];
#pragma unroll
    for (int k = 0; k < 32; k++) f1c[k] = fw1[k * 64 + lane];
#pragma unroll
    for (int k = 0; k < 64; k++) f2c[k] = fw2[k * 64 + lane];
    float fb1v = fb1[lane], fb2v = fb2[lane];
    float* s0 = sh[wid];
    const float4* s4 = (const float4*)s0;

    int npairs = (n + 1) >> 1;
    int gw = blockIdx.x * 4 + wid, nw = gridDim.x * 4;
    int total = n * 32;
    for (int pair = gw; pair < npairs; pair += nw) {
        int idx = pair * 64 + lane;
        s0[lane] = (idx < total) ? xn[idx] : 0.f;
        float u0, u1;
        {
            float a0 = 0, a1 = 0, b0 = 0, b1 = 0;
#pragma unroll
            for (int k = 0; k < 8; k++) {
                float4 t = s4[k];
                float4 t2 = s4[8 + k];
                a0 += t.x * f1c[4 * k] + t.y * f1c[4 * k + 1];
                a1 += t.z * f1c[4 * k + 2] + t.w * f1c[4 * k + 3];
                b0 += t2.x * f1c[4 * k] + t2.y * f1c[4 * k + 1];
                b1 += t2.z * f1c[4 * k + 2] + t2.w * f1c[4 * k + 3];
            }
            u0 = fmaxf(fb1v + a0 + a1, 0.f);
            u1 = fmaxf(fb1v + b0 + b1, 0.f);
        }
        s0[lane] = u0;
        s0[64 + lane] = u1;
        float o0, o1;
        {
            float a0 = 0, a1 = 0, b0 = 0, b1 = 0;
#pragma unroll
            for (int k = 0; k < 16; k++) {
                float4 t = s4[k];
                float4 t2 = s4[16 + k];
                a0 += t.x * f2c[4 * k] + t.y * f2c[4 * k + 1];
                a1 += t.z * f2c[4 * k + 2] + t.w * f2c[4 * k + 3];
                b0 += t2.x * f2c[4 * k] + t2.y * f2c[4 * k + 1];
                b1 += t2.z * f2c[4 * k + 2] + t2.w * f2c[4 * k + 3];
            }
            o0 = fmaxf(fb2v + a0 + a1, 0.f);
            o1 = fmaxf(fb2v + b0 + b1, 0.f);
        }
        int n0 = pair * 2;
        xout[(size_t)n0 * 64 + lane] = o0;
        if (n0 + 1 < n) xout[(size_t)(n0 + 1) * 64 + lane] = o1;
    }
}

// ================ dense transform h = x @ W (64 -> COUT), bf16 output ================
template <int COUT, bool DO_ATTN, bool SCALE>
__global__ __launch_bounds__(256) void k_transform(
    const float* __restrict__ x, const float* __restrict__ w,
    const float* __restrict__ asrc, const float* __restrict__ adst,
    const float* __restrict__ inv, __hip_bfloat16* __restrict__ h,
    float* __restrict__ attn, int n) {
    constexpr int NPG = 64 / COUT;  // nodes per wave
    __shared__ __align__(16) float scr[4][NPG * 64];
    int tid = threadIdx.x, wid = tid >> 6, lane = tid & 63;
    int ch = lane % COUT;
    int sub = lane / COUT;
    float wr[64];
#pragma unroll
    for (int k = 0; k < 64; k++) wr[k] = w[k * COUT + ch];
    float as_r = 0.f, ad_r = 0.f;
    if (DO_ATTN) {
        as_r = asrc[lane];
        ad_r = adst[lane];
    }
    int ngroups = (n + NPG - 1) / NPG;
    int gw = blockIdx.x * 4 + wid, nw = gridDim.x * 4;
    int total = n * 64;
    unsigned int* h2 = (unsigned int*)h;
    for (int g = gw; g < ngroups; g += nw) {
        int base = g * NPG * 64;
#pragma unroll
        for (int i = 0; i < NPG; i++) {
            int idx = i * 64 + lane;
            scr[wid][idx] = (base + idx < total) ? x[base + idx] : 0.f;
        }
        float acc0 = 0.f, acc1 = 0.f;
        const float4* sp4 = (const float4*)(&scr[wid][sub * 64]);
#pragma unroll
        for (int k = 0; k < 16; k++) {
            float4 t = sp4[k];
            acc0 += t.x * wr[4 * k] + t.y * wr[4 * k + 1];
            acc1 += t.z * wr[4 * k + 2] + t.w * wr[4 * k + 3];
        }
        float acc = acc0 + acc1;
        int node = g * NPG + sub;
        if (SCALE) acc *= (node < n) ? inv[node] : 0.f;
        unsigned int mine = f2bf_bits(acc);
        unsigned int oth = (unsigned int)__shfl_xor((int)mine, 1, 64);
        if ((ch & 1) == 0 && node < n)
            h2[(size_t)node * (COUT / 2) + (ch >> 1)] = mine | (oth << 16);
        if (DO_ATTN) {
            float ps = acc * as_r, pd = acc * ad_r;
#pragma unroll
            for (int off = 16; off; off >>= 1) {
                ps += __shfl_xor(ps, off, 64);
                pd += __shfl_xor(pd, off, 64);
            }
            if ((lane & 31) == 0 && node < n) {
                int hd = lane >> 5;
                attn[node * 4 + hd] = ps;       // alpha_src
                attn[node * 4 + 2 + hd] = pd;   // alpha_dst
            }
        }
    }
}

// ================ GCN aggregation + bias + BN + ReLU (pre-scaled bf16 h') ================
// R14 structure: maskless (dummy row), NE*8-edge step.
template <int C>
__global__ __launch_bounds__(256) void k_gcn_agg(
    const __hip_bfloat16* __restrict__ h, const int* __restrict__ rowp,
    const int* __restrict__ csrc, const float* __restrict__ inv,
    const float* __restrict__ bias, const float* __restrict__ bg,
    const float* __restrict__ bb, const float* __restrict__ bm,
    const float* __restrict__ bv, float* __restrict__ out, int n, int dummy) {
    constexpr int LPE = C / 2;
    constexpr int NE = 64 / LPE;
    int tid = threadIdx.x, lane = tid & 63;
    int node = blockIdx.x * 4 + (tid >> 6);
    if (node >= n) return;
    float invd = inv[node];
    int e0 = rowp[node], e1 = rowp[node + 1];
    int l = lane & (LPE - 1);
    int grp = lane / LPE;
    const unsigned int* h2 = (const unsigned int*)h;
    float acc0 = 0.f, acc1 = 0.f;
    for (int cb = e0; cb < e1; cb += 64) {
        int kn = min(64, e1 - cb);
        int s_l = (lane < kn) ? csrc[cb + lane] : dummy;  // dummy row = zeros
        for (int kb = 0; kb < kn; kb += NE * 8) {
            unsigned int v[8];
#pragma unroll
            for (int i = 0; i < 8; i++) {
                int k = kb + i * NE + grp;
                int s = __shfl(s_l, k, 64);
                v[i] = h2[(size_t)s * LPE + l];
            }
#pragma unroll
            for (int i = 0; i < 8; i++) {
                acc0 += bf_lo(v[i]);
                acc1 += bf_hi(v[i]);
            }
        }
    }
#pragma unroll
    for (int off = LPE; off < 64; off <<= 1) {
        acc0 += __shfl_xor(acc0, off, 64);
        acc1 += __shfl_xor(acc1, off, 64);
    }
    unsigned int sv = h2[(size_t)node * LPE + l];
    acc0 = (acc0 + bf_lo(sv)) * invd;
    acc1 = (acc1 + bf_hi(sv)) * invd;
    if (grp == 0) {
        int c0 = 2 * l;
        float sc0 = bg[c0] * rsqrtf(bv[c0] + EPS);
        float sc1 = bg[c0 + 1] * rsqrtf(bv[c0 + 1] + EPS);
        float r0 = (acc0 + bias[c0] - bm[c0]) * sc0 + bb[c0];
        float r1 = (acc1 + bias[c0 + 1] - bm[c0 + 1]) * sc1 + bb[c0 + 1];
        ((float2*)out)[(size_t)node * LPE + l] = make_float2(fmaxf(r0, 0.f), fmaxf(r1, 0.f));
    }
}

// ================ GAT aggregation + bias + BN + ReLU (bf16 h) ================
// R14 structure: no segment-max (exp direct, clamp 60), 16-edge step,
// edge slots packed uint2{src, bf16 exp-weights} in wave-private LDS.
__global__ __launch_bounds__(256) void k_gat_agg(
    const __hip_bfloat16* __restrict__ h, const int* __restrict__ rowp,
    const int* __restrict__ csrc, const float* __restrict__ attn,
    const float* __restrict__ bias, const float* __restrict__ bg,
    const float* __restrict__ bb, const float* __restrict__ bm,
    const float* __restrict__ bv, float* __restrict__ out, int n) {
    __shared__ uint2 sed[4][64];
    int tid = threadIdx.x, lane = tid & 63, wid = tid >> 6;
    int node = blockIdx.x * 4 + wid;
    if (node >= n) return;
    uint2* se = sed[wid];
    const float4* a4p = (const float4*)attn;
    float4 ad = a4p[node];
    float ad0 = ad.z, ad1 = ad.w;
    float exs0 = __expf(fminf(lrelu02(ad.x + ad0), 60.f));  // self edge
    float exs1 = __expf(fminf(lrelu02(ad.y + ad1), 60.f));
    int e0 = rowp[node], e1 = rowp[node + 1];
    int deg = e1 - e0;
    int kn0 = min(deg, 64);
    int s_l = (lane < kn0) ? csrc[e0 + lane] : node;
    float4 a_l = a4p[s_l];
    float ex0 = (lane < kn0) ? __expf(fminf(lrelu02(a_l.x + ad0), 60.f)) : 0.f;
    float ex1 = (lane < kn0) ? __expf(fminf(lrelu02(a_l.y + ad1), 60.f)) : 0.f;
    float t0 = ex0, t1 = ex1;
    se[lane] = make_uint2((unsigned int)s_l, f2bf_bits(ex0) | (f2bf_bits(ex1) << 16));
    int l = lane & 31, grp = lane >> 5;
    bool hd2 = l >= 16;  // channels 2l,2l+1 belong to head (l>=16)
    const unsigned int* h2 = (const unsigned int*)h;
    float acc0 = 0.f, acc1 = 0.f;
    for (int kb = 0; kb < kn0; kb += 16) {
        unsigned int v[8];
        float wg[8];
#pragma unroll
        for (int i = 0; i < 8; i++) {
            int k = kb + i * 2 + grp;
            uint2 e = se[k];  // broadcast within group (2-way: free)
            wg[i] = hd2 ? bf_hi(e.y) : bf_lo(e.y);
            v[i] = h2[(size_t)e.x * 32 + l];
        }
#pragma unroll
        for (int i = 0; i < 8; i++) {
            acc0 += wg[i] * bf_lo(v[i]);
            acc1 += wg[i] * bf_hi(v[i]);
        }
    }
    // extra chunks (deg > 64)
    for (int cb = e0 + 64; cb < e1; cb += 64) {
        int kn = min(64, e1 - cb);
        int s_c = (lane < kn) ? csrc[cb + lane] : node;
        float4 a_c = a4p[s_c];
        float c0 = (lane < kn) ? __expf(fminf(lrelu02(a_c.x + ad0), 60.f)) : 0.f;
        float c1 = (lane < kn) ? __expf(fminf(lrelu02(a_c.y + ad1), 60.f)) : 0.f;
        t0 += c0;
        t1 += c1;
        se[lane] = make_uint2((unsigned int)s_c, f2bf_bits(c0) | (f2bf_bits(c1) << 16));
        for (int kb = 0; kb < kn; kb += 16) {
            unsigned int v[8];
            float wg[8];
#pragma unroll
            for (int i = 0; i < 8; i++) {
                int k = kb + i * 2 + grp;
                uint2 e = se[k];
                wg[i] = hd2 ? bf_hi(e.y) : bf_lo(e.y);
                v[i] = h2[(size_t)e.x * 32 + l];
            }
#pragma unroll
            for (int i = 0; i < 8; i++) {
                acc0 += wg[i] * bf_lo(v[i]);
                acc1 += wg[i] * bf_hi(v[i]);
            }
        }
    }
#pragma unroll
    for (int off = 32; off; off >>= 1) {
        t0 += __shfl_xor(t0, off, 64);
        t1 += __shfl_xor(t1, off, 64);
    }
    t0 += exs0;
    t1 += exs1;
    acc0 += __shfl_xor(acc0, 32, 64);
    acc1 += __shfl_xor(acc1, 32, 64);
    unsigned int sv = h2[(size_t)node * 32 + l];
    float ws = hd2 ? exs1 : exs0;
    acc0 += ws * bf_lo(sv);
    acc1 += ws * bf_hi(sv);
    float rsh = hd2 ? (1.f / (t1 + 1e-16f)) : (1.f / (t0 + 1e-16f));
    acc0 *= rsh;
    acc1 *= rsh;
    if (grp == 0) {
        int c0 = 2 * l;
        float sc0 = bg[c0] * rsqrtf(bv[c0] + EPS);
        float sc1 = bg[c0 + 1] * rsqrtf(bv[c0 + 1] + EPS);
        float r0 = (acc0 + bias[c0] - bm[c0]) * sc0 + bb[c0];
        float r1 = (acc1 + bias[c0 + 1] - bm[c0 + 1]) * sc1 + bb[c0 + 1];
        ((float2*)out)[(size_t)node * 32 + l] = make_float2(fmaxf(r0, 0.f), fmaxf(r1, 0.f));
    }
}

// ================ SVI head: relu(x@W1+b1)@W2+b2 -> sigmoid ================
__global__ __launch_bounds__(256) void k_head(
    const float* __restrict__ x, const float* __restrict__ w1, const float* __restrict__ b1,
    const float* __restrict__ w2, const float* __restrict__ b2, float* __restrict__ out, int n) {
    __shared__ float sw1[512], sb1[16], sw2[16];
    __shared__ float sb2v;
    __shared__ float scr[4][64];
    int tid = threadIdx.x;
    for (int i = tid; i < 512; i += 256) sw1[i] = w1[i];
    if (tid < 16) {
        sb1[tid] = b1[tid];
        sw2[tid] = w2[tid];
    }
    if (tid == 0) sb2v = b2[0];
    __syncthreads();
    int wid = tid >> 6, lane = tid & 63;
    int half = lane >> 5;
    int np = (n + 1) >> 1;
    int gw = blockIdx.x * 4 + wid, nw = gridDim.x * 4;
    int total = n * 32;
    for (int g = gw; g < np; g += nw) {
        int idx = g * 64 + lane;
        scr[wid][lane] = (idx < total) ? x[idx] : 0.f;
        int j = lane & 15;
        float u = sb1[j];
#pragma unroll
        for (int k = 0; k < 32; k++) u += scr[wid][half * 32 + k] * sw1[k * 16 + j];
        u = fmaxf(u, 0.f);
        float p = u * sw2[j];
#pragma unroll
        for (int off = 8; off; off >>= 1) p += __shfl_xor(p, off, 64);
        int node = g * 2 + half;
        if ((lane & 31) == 0 && node < n) {
            float z = p + sb2v;
            out[node] = 1.f / (1.f + __expf(-z));
        }
    }
}

// ======================= launcher =======================
extern "C" void kernel_launch(void* const* d_in, const int* in_sizes, int n_in,
                              void* d_out, int out_size, void* d_ws, size_t ws_size,
                              hipStream_t stream) {
    const float* accf = (const float*)d_in[0];
    const float* ctxf = (const float*)d_in[1];
    const int* ei = (const int*)d_in[2];
    const float* cg_w1 = (const float*)d_in[3];
    const float* cg_b1 = (const float*)d_in[4];
    const float* cg_w2 = (const float*)d_in[5];
    const float* cg_b2 = (const float*)d_in[6];
    const float* cg_aw = (const float*)d_in[7];
    const float* cg_ab = (const float*)d_in[8];
    const float* base_imp = (const float*)d_in[9];
    const float* ln_g = (const float*)d_in[10];
    const float* ln_b = (const float*)d_in[11];
    const float* fe_w1 = (const float*)d_in[12];
    const float* fe_b1 = (const float*)d_in[13];
    const float* fe_w2 = (const float*)d_in[14];
    const float* fe_b2 = (const float*)d_in[15];
    const float* gcn1_w = (const float*)d_in[16];
    const float* gcn1_b = (const float*)d_in[17];
    const float* bn1_g = (const float*)d_in[18];
    const float* bn1_b = (const float*)d_in[19];
    const float* bn1_m = (const float*)d_in[20];
    const float* bn1_v = (const float*)d_in[21];
    const float* gat_w = (const float*)d_in[22];
    const float* gat_asrc = (const float*)d_in[23];
    const float* gat_adst = (const float*)d_in[24];
    const float* gat_b = (const float*)d_in[25];
    const float* bn2_g = (const float*)d_in[26];
    const float* bn2_b = (const float*)d_in[27];
    const float* bn2_m = (const float*)d_in[28];
    const float* bn2_v = (const float*)d_in[29];
    const float* gcn2_w = (const float*)d_in[30];
    const float* gcn2_b = (const float*)d_in[31];
    const float* bn3_g = (const float*)d_in[32];
    const float* bn3_b = (const float*)d_in[33];
    const float* bn3_m = (const float*)d_in[34];
    const float* bn3_v = (const float*)d_in[35];
    const float* sp_w1 = (const float*)d_in[36];
    const float* sp_b1 = (const float*)d_in[37];
    const float* sp_w2 = (const float*)d_in[38];
    const float* sp_b2 = (const float*)d_in[39];

    int n = in_sizes[0] / A_DIM;  // 100000
    int E = in_sizes[2] / 2;      // 1600000
    int NB = (n + 127) >> 7;      // 782 buckets of 128 nodes

    char* p = (char*)d_ws;
    auto alloc = [&](size_t bytes) -> void* {
        void* r = (void*)p;
        p += (bytes + 255) & ~(size_t)255;
        return r;
    };
    float* X = (float*)alloc((size_t)n * 64 * 4);
    __hip_bfloat16* Hb = (__hip_bfloat16*)alloc((size_t)n * 64 * 2 + 256);  // +dummy rows
    float* attn = (float*)alloc((size_t)n * 4 * 4);
    float* XN = (float*)alloc((size_t)n * 32 * 4);
    int* rowp = (int*)alloc((size_t)(n + 1) * 4);
    float* inv = (float*)alloc((size_t)n * 4);
    int* csrc = (int*)alloc((size_t)E * 4);
    int* bcnt = (int*)alloc((size_t)NB * 16 * 4);  // padded: 1 counter / 64B line
    int* bstage = (int*)alloc((size_t)NB * BCAP * 4);

    // --- CSR build (bucket counting sort; LDS-sorted pass A) ---
    hipMemsetAsync(bcnt, 0, (size_t)NB * 16 * 4, stream);
    // zero dummy rows: bytes [128n, 128n+192) cover C=64 dummy (row n) and
    // C=32 dummy (row 2n+2); no transform ever writes >= byte 128n.
    hipMemsetAsync((char*)Hb + (size_t)128 * n, 0, 192, stream);
    k_bucketA<<<(E + EPB - 1) / EPB, 256, 0, stream>>>(ei, E, bcnt, bstage, NB);
    k_bucketB<<<NB, 256, 0, stream>>>(bstage, bcnt, rowp, inv, csrc, n, NB);

    // --- node pipeline ---
    k_gate<<<1024, 256, 0, stream>>>(accf, ctxf, cg_w1, cg_b1, cg_w2, cg_b2, cg_aw, cg_ab,
                                     base_imp, ln_g, ln_b, XN, n);
    k_encode<<<1024, 256, 0, stream>>>(XN, fe_w1, fe_b1, fe_w2, fe_b2, X, n);
    // GCN1 (pre-scaled h'); dummy row = n
    k_transform<64, false, true><<<1024, 256, 0, stream>>>(X, gcn1_w, nullptr, nullptr, inv, Hb,
                                                           nullptr, n);
    k_gcn_agg<64><<<(n + 3) / 4, 256, 0, stream>>>(Hb, rowp, csrc, inv, gcn1_b, bn1_g, bn1_b,
                                                   bn1_m, bn1_v, X, n, n);
    // GAT (unscaled h)
    k_transform<64, true, false><<<1024, 256, 0, stream>>>(X, gat_w, gat_asrc, gat_adst, nullptr,
                                                           Hb, attn, n);
    k_gat_agg<<<(n + 3) / 4, 256, 0, stream>>>(Hb, rowp, csrc, attn, gat_b, bn2_g, bn2_b, bn2_m,
                                               bn2_v, X, n);
    // GCN2 (pre-scaled h'); dummy row = 2n+2
    k_transform<32, false, true><<<1024, 256, 0, stream>>>(X, gcn2_w, nullptr, nullptr, inv, Hb,
                                                           nullptr, n);
    k_gcn_agg<32><<<(n + 3) / 4, 256, 0, stream>>>(Hb, rowp, csrc, inv, gcn2_b, bn3_g, bn3_b,
                                                   bn3_m, bn3_v, X, n, 2 * n + 2);
    // head
    k_head<<<512, 256, 0, stream>>>(X, sp_w1, sp_b1, sp_w2, sp_b2, (float*)d_out, n);
}